// Round 9
// baseline (121.632 us; speedup 1.0000x reference)
//
#include <hip/hip_runtime.h>
#include <cstdint>

typedef __attribute__((ext_vector_type(8))) short bfrag_t;   // 8 x bf16 (4 VGPR)
typedef __attribute__((ext_vector_type(4))) float f32x4_t;   // MFMA acc

#define MFMA16(a,b,c) __builtin_amdgcn_mfma_f32_16x16x32_bf16((a),(b),(c),0,0,0)

__device__ __forceinline__ unsigned short f2bf(float f){
  unsigned u = __float_as_uint(f);
  unsigned r = u + 0x7fffu + ((u >> 16) & 1u);   // round-to-nearest-even
  return (unsigned short)(r >> 16);
}

// pack 2 f32 -> 2 bf16 in one u32 (lo = a, hi = b)
__device__ __forceinline__ unsigned pk2bf(float a, float b){
  unsigned r;
  asm("v_cvt_pk_bf16_f32 %0, %1, %2" : "=v"(r) : "v"(a), "v"(b));
  return r;
}

// async global->LDS, 16B per lane. LDS dest = wave-uniform base + lane*16.
__device__ __forceinline__ void gload16(const unsigned short* g, unsigned short* l){
  __builtin_amdgcn_global_load_lds(
      (const __attribute__((address_space(1))) unsigned int*)(const void*)g,
      (__attribute__((address_space(3))) unsigned int*)(void*)l,
      16, 0, 0);
}

// ---------------- f32 -> bf16 convert (vectorized) ----------------
__global__ __launch_bounds__(256) void k_cvt(const float* __restrict__ in,
                                             unsigned short* __restrict__ out, int n4){
  int i = blockIdx.x*blockDim.x + threadIdx.x;
  int stride = gridDim.x*blockDim.x;
  for(; i < n4; i += stride){
    float4 v = ((const float4*)in)[i];
    ushort4 o;
    o.x = f2bf(v.x); o.y = f2bf(v.y); o.z = f2bf(v.z); o.w = f2bf(v.w);
    ((ushort4*)out)[i] = o;
  }
}

// ---------------- f32 [R][C] -> bf16 [C][R] transpose ----------------
__global__ __launch_bounds__(256) void k_transpose(const float* __restrict__ in,
                                                   unsigned short* __restrict__ out,
                                                   int R, int C){
  __shared__ unsigned short tile[32][33];
  int bc = blockIdx.x*32, br = blockIdx.y*32;
  int tx = threadIdx.x & 31, ty = threadIdx.x >> 5;  // ty 0..7
  #pragma unroll
  for(int i=0;i<32;i+=8){
    tile[ty+i][tx] = f2bf(in[(size_t)(br+ty+i)*C + bc + tx]);
  }
  __syncthreads();
  #pragma unroll
  for(int i=0;i<32;i+=8){
    out[(size_t)(bc+ty+i)*R + br + tx] = tile[tx][ty+i];
  }
}

// ---------------- GEMM1: x @ w_qkv -> Q (scaled), K image, V image ----------
// 128x128 tile, BK=64, 2-phase double-buffered LDS (64KB): one barrier/iter,
// stage(t+1) issued right after the barrier -> loads fly during MFMA phase,
// so the compiler's pre-barrier vmcnt(0) drain is nearly free.
// 8-slot source-side XOR swizzle (gs = s ^ (row&7)), matching XOR on read.
// Block-uniform branch: bn<2048 -> swapped core (Q/K, uint2 stores);
//                       bn>=2048 -> normal core (V image, uint2 stores).
__global__ __launch_bounds__(256) void k_gemm1(
    const unsigned short* __restrict__ A,    // x bf16 [4096][1024]
    const unsigned short* __restrict__ Bt,   // wqkvT [3072][1024]
    unsigned short* __restrict__ Qo, unsigned short* __restrict__ Kimg,
    unsigned short* __restrict__ Vimg)
{
  __shared__ unsigned short ldsA[2*128*64];
  __shared__ unsigned short ldsB[2*128*64];

  const int tid = threadIdx.x;
  const int lane = tid & 63;
  const int w = tid >> 6;
  const int wr = w >> 1, wc = w & 1;
  const int col16 = lane & 15, g = lane >> 4;
  const int bm = blockIdx.y * 128;
  const int bn = blockIdx.x * 128;
  const int K = 1024;
  const int SWAP = (bn < 2048) ? 1 : 0;

  f32x4_t acc[4][4];
  #pragma unroll
  for(int i=0;i<4;i++)
    #pragma unroll
    for(int j=0;j<4;j++) acc[i][j] = (f32x4_t)0.0f;

  auto stage = [&](int k0, int bsel){
    unsigned short* la = ldsA + bsel*(128*64);
    unsigned short* lb = ldsB + bsel*(128*64);
    #pragma unroll
    for(int i=0; i<4; i++){                 // A: 128 rows x 8 slots = 1024 units
      int u = i*256 + tid;
      int row = u>>3, s = u&7, gs = s ^ (row&7);
      gload16(A + (size_t)(bm+row)*K + k0 + gs*8, la + (i*256 + w*64)*8);
    }
    #pragma unroll
    for(int i=0; i<4; i++){                 // B: 1024 units
      int u = i*256 + tid;
      int row = u>>3, s = u&7, gs = s ^ (row&7);
      gload16(Bt + (size_t)(bn+row)*K + k0 + gs*8, lb + (i*256 + w*64)*8);
    }
  };

  stage(0, 0);
  int cur = 0;
  for(int k0=0; k0<K; k0+=64){
    __syncthreads();   // drains buf[cur] loads (in flight since last iter) +
                       // all waves past their reads of buf[cur^1]
    if (k0+64 < K) stage(k0+64, cur^1);    // prefetch overlaps compute below
    const unsigned short* la = ldsA + cur*(128*64);
    const unsigned short* lb = ldsB + cur*(128*64);
    #pragma unroll
    for(int kk=0; kk<2; kk++){
      bfrag_t af[4], bfr[4];
      #pragma unroll
      for(int mi=0;mi<4;mi++){
        int row = wr*64 + mi*16 + col16;
        int slot = (kk*4 + g) ^ (row&7);
        af[mi] = *(const bfrag_t*)(la + row*64 + slot*8);
      }
      #pragma unroll
      for(int ni=0;ni<4;ni++){
        int row = wc*64 + ni*16 + col16;
        int slot = (kk*4 + g) ^ (row&7);
        bfr[ni] = *(const bfrag_t*)(lb + row*64 + slot*8);
      }
      if (SWAP){
        #pragma unroll
        for(int mi=0;mi<4;mi++)
          #pragma unroll
          for(int ni=0;ni<4;ni++)
            acc[mi][ni] = MFMA16(bfr[ni], af[mi], acc[mi][ni]);
      } else {
        #pragma unroll
        for(int mi=0;mi<4;mi++)
          #pragma unroll
          for(int ni=0;ni<4;ni++)
            acc[mi][ni] = MFMA16(af[mi], bfr[ni], acc[mi][ni]);
      }
    }
    cur ^= 1;
  }

  if (bn < 2048){
    // lane holds C[s = row][4 consecutive n]; which uniform per block
    const int which = bn >> 10;   // 0 = Q, 1 = K
    #pragma unroll
    for(int mi=0;mi<4;mi++){
      int s_full = bm + wr*64 + mi*16 + col16;
      int b = s_full >> 11, sq = s_full & 2047;
      #pragma unroll
      for(int ni=0;ni<4;ni++){
        int n0 = bn + wc*64 + ni*16 + g*4;
        int h = (n0 & 1023) >> 6;
        int d0 = n0 & 63;
        size_t bh = (size_t)(b*16 + h);
        float v0 = acc[mi][ni][0], v1 = acc[mi][ni][1];
        float v2 = acc[mi][ni][2], v3 = acc[mi][ni][3];
        if (which == 0){
          const float sc = 0.18033688f;   // 0.125 * log2(e): exp2-domain softmax
          uint2 pkd; pkd.x = pk2bf(v0*sc, v1*sc); pkd.y = pk2bf(v2*sc, v3*sc);
          *(uint2*)(Qo + (bh*2048 + sq)*64 + d0) = pkd;
        } else {
          int kt = sq >> 6, rr = sq & 63;
          int ks = rr >> 4, c16i = rr & 15;
          int dk = d0 >> 5, g3 = (d0 >> 3) & 3, e0 = d0 & 7;
          uint2 pkd; pkd.x = pk2bf(v0, v1); pkd.y = pk2bf(v2, v3);
          size_t off = bh*131072 + (size_t)kt*4096
                     + (size_t)(ks*2 + dk)*512 + (size_t)(g3*16 + c16i)*8 + e0;
          *(uint2*)(Kimg + off) = pkd;
        }
      }
    }
  } else {
    // V: lane holds 4 consecutive s (packs along e) -> uint2
    #pragma unroll
    for(int mi=0;mi<4;mi++){
      int s0 = bm + wr*64 + mi*16 + g*4;
      int b = s0 >> 11, sq0 = s0 & 2047;
      int kt = sq0 >> 6, sc0 = sq0 & 63;
      int jk = sc0 >> 5, g3 = (sc0 >> 3) & 3, e0 = sc0 & 7;
      #pragma unroll
      for(int ni=0;ni<4;ni++){
        int ncol = bn + wc*64 + ni*16 + col16;
        int h = (ncol & 1023) >> 6;
        int d64 = ncol & 63;
        int nimg = d64 >> 4, c16i = d64 & 15;
        size_t bh = (size_t)(b*16 + h);
        uint2 pkd;
        pkd.x = pk2bf(acc[mi][ni][0], acc[mi][ni][1]);
        pkd.y = pk2bf(acc[mi][ni][2], acc[mi][ni][3]);
        size_t off = bh*131072 + (size_t)kt*4096
                   + (size_t)(nimg*2 + jk)*512 + (size_t)(g3*16 + c16i)*8 + e0;
        *(uint2*)(Vimg + off) = pkd;
      }
    }
  }
}

// ---------------- GEMM2: attn_out @ w_out + bias -> f32 ---------------------
// 64x128 tile, BK=64, 2-phase double-buffered LDS (48KB), one barrier/iter.
__global__ __launch_bounds__(256) void k_gemm2(
    const unsigned short* __restrict__ A,    // attn_out bf16 [4096][1024]
    const unsigned short* __restrict__ Bt,   // woutT [1024][1024]
    float* __restrict__ Co, const float* __restrict__ bias)
{
  __shared__ unsigned short ldsA[2*64*64];
  __shared__ unsigned short ldsB[2*128*64];

  const int tid = threadIdx.x;
  const int lane = tid & 63;
  const int w = tid >> 6;
  const int wc = w;                       // WM=1, WN=4
  const int col16 = lane & 15, g = lane >> 4;
  const int bm = blockIdx.y * 64;
  const int bn = blockIdx.x * 128;
  const int K = 1024, N = 1024;

  f32x4_t acc[4][2];
  #pragma unroll
  for(int i=0;i<4;i++)
    #pragma unroll
    for(int j=0;j<2;j++) acc[i][j] = (f32x4_t)0.0f;

  auto stage = [&](int k0, int bsel){
    unsigned short* la = ldsA + bsel*(64*64);
    unsigned short* lb = ldsB + bsel*(128*64);
    #pragma unroll
    for(int i=0; i<2; i++){                 // A: 64 rows x 8 slots = 512 units
      int u = i*256 + tid;
      int row = u>>3, s = u&7, gs = s ^ (row&7);
      gload16(A + (size_t)(bm+row)*K + k0 + gs*8, la + (i*256 + w*64)*8);
    }
    #pragma unroll
    for(int i=0; i<4; i++){                 // B: 1024 units
      int u = i*256 + tid;
      int row = u>>3, s = u&7, gs = s ^ (row&7);
      gload16(Bt + (size_t)(bn+row)*K + k0 + gs*8, lb + (i*256 + w*64)*8);
    }
  };

  stage(0, 0);
  int cur = 0;
  for(int k0=0; k0<K; k0+=64){
    __syncthreads();
    if (k0+64 < K) stage(k0+64, cur^1);
    const unsigned short* la = ldsA + cur*(64*64);
    const unsigned short* lb = ldsB + cur*(128*64);
    #pragma unroll
    for(int kk=0; kk<2; kk++){
      bfrag_t af[4], bfr[2];
      #pragma unroll
      for(int mi=0;mi<4;mi++){
        int row = mi*16 + col16;
        int slot = (kk*4 + g) ^ (row&7);
        af[mi] = *(const bfrag_t*)(la + row*64 + slot*8);
      }
      #pragma unroll
      for(int ni=0;ni<2;ni++){
        int row = wc*32 + ni*16 + col16;
        int slot = (kk*4 + g) ^ (row&7);
        bfr[ni] = *(const bfrag_t*)(lb + row*64 + slot*8);
      }
      #pragma unroll
      for(int mi=0;mi<4;mi++)
        #pragma unroll
        for(int ni=0;ni<2;ni++)
          acc[mi][ni] = MFMA16(af[mi], bfr[ni], acc[mi][ni]);
    }
    cur ^= 1;
  }

  #pragma unroll
  for(int mi=0;mi<4;mi++){
    int mrow = bm + mi*16 + g*4;
    #pragma unroll
    for(int ni=0;ni<2;ni++){
      int ncol = bn + wc*32 + ni*16 + col16;
      float bb = bias[ncol];
      #pragma unroll
      for(int r=0;r<4;r++){
        Co[(size_t)(mrow+r)*N + ncol] = acc[mi][ni][r] + bb;
      }
    }
  }
}

// ---------------- causal flash attention (v8: balanced cohorts + setprio) ----
// grid (32 bh, 32 y). All 1024 blocks co-resident (4/CU); a CU's cohort is
// y = {j, j+8, j+16, j+24}. Map idx=(y&7)*4+(y>>3); qt=(idx&1)?31-(idx>>1):idx>>1
// -> every cohort's nkt sum = 66 (exact balance).
// 256 threads = 4 waves; wave w owns q rows qt*64+w*16..+15; lane (g,c) owns
// q row qt*64+w*16+c. Swapped QK^T and PV (S^T, O^T in regs).
// Q pre-scaled by 0.125*log2e -> P = exp2(S' - m'). defer-max THR = 8*log2e.
__global__ __launch_bounds__(256, 4) void k_attn(
    const unsigned short* __restrict__ Q,
    const unsigned short* __restrict__ Kimg,
    const unsigned short* __restrict__ Vimg,
    unsigned short* __restrict__ O)
{
  __shared__ unsigned short kls[2*4096];     // K tiles, double-buffered (8KB each)
  __shared__ unsigned short vls[2*4096];     // V tiles
  __shared__ unsigned short plds[4*1024];    // per-wave 16x64 P tile, XOR-swizzled
  const int lane = threadIdx.x & 63;
  const int w = threadIdx.x >> 6;
  const int col16 = lane & 15, g = lane >> 4;
  const int bh = blockIdx.x;
  const int y = blockIdx.y;
  const int idx = (y & 7)*4 + (y >> 3);
  const int qt = (idx & 1) ? (31 - (idx >> 1)) : (idx >> 1);
  const int b = bh >> 4, h = bh & 15;

  const unsigned short* Qb = Q    + (size_t)bh*2048*64;
  const unsigned short* Kb = Kimg + (size_t)bh*131072;
  const unsigned short* Vb = Vimg + (size_t)bh*131072;
  char* pw = (char*)(plds + w*1024);

  auto stage = [&](int kt, int bsel){
    const unsigned short* gk = Kb + (size_t)kt*4096;
    const unsigned short* gv = Vb + (size_t)kt*4096;
    unsigned short* lk = kls + bsel*4096;
    unsigned short* lv = vls + bsel*4096;
    #pragma unroll
    for(int c=0;c<2;c++){
      int chunk = w*2 + c;               // 0..7, 1KB each
      int u = chunk*64 + lane;           // 16B-unit index
      gload16(gk + u*8, lk + chunk*512);
      gload16(gv + u*8, lv + chunk*512);
    }
  };

  const int qrow0 = qt*64 + w*16;
  const int nkt = qt + 1;
  const int qi = qrow0 + col16;          // this lane's q row

  bfrag_t qf[2];
  #pragma unroll
  for(int dk=0;dk<2;dk++)
    qf[dk] = *(const bfrag_t*)(Qb + (size_t)(qrow0 + col16)*64 + dk*32 + g*8);

  f32x4_t oaccT[4];
  #pragma unroll
  for(int n=0;n<4;n++) oaccT[n] = (f32x4_t)0.0f;
  float mrun = -1e30f, lrun = 0.f;

  stage(0, 0);
  __syncthreads();

  #pragma unroll 1
  for(int kt=0; kt<nkt; kt++){
    const int cur = kt & 1;
    if (kt+1 < nkt) stage(kt+1, cur^1);

    const bfrag_t* kb = (const bfrag_t*)(kls + cur*4096);
    const bfrag_t* vb = (const bfrag_t*)(vls + cur*4096);

    // ---- S'^T = K Q^T (exp2 domain): sacc[ks][r] = S'[q=qi][k=kt*64+ks*16+g*4+r]
    f32x4_t sacc[4];
    __builtin_amdgcn_s_setprio(1);
    #pragma unroll
    for(int ks=0; ks<4; ks++){
      bfrag_t kf0 = kb[(ks*2+0)*64 + lane];
      bfrag_t kf1 = kb[(ks*2+1)*64 + lane];
      f32x4_t c = (f32x4_t)0.0f;
      c = MFMA16(kf0, qf[0], c);
      c = MFMA16(kf1, qf[1], c);
      sacc[ks] = c;
    }
    __builtin_amdgcn_s_setprio(0);
    // ---- causal mask (diagonal tile only) ----
    if (kt == qt){
      const int kbase = kt*64;
      #pragma unroll
      for(int ks=0; ks<4; ks++)
        #pragma unroll
        for(int r=0;r<4;r++){
          int kj = kbase + ks*16 + g*4 + r;
          if (kj > qi) sacc[ks][r] = -1e30f;
        }
    }
    // ---- per-lane row max + 2 shfl ----
    float pm = fmaxf(
        fmaxf(fmaxf(fmaxf(sacc[0][0],sacc[0][1]),fmaxf(sacc[0][2],sacc[0][3])),
              fmaxf(fmaxf(sacc[1][0],sacc[1][1]),fmaxf(sacc[1][2],sacc[1][3]))),
        fmaxf(fmaxf(fmaxf(sacc[2][0],sacc[2][1]),fmaxf(sacc[2][2],sacc[2][3])),
              fmaxf(fmaxf(sacc[3][0],sacc[3][1]),fmaxf(sacc[3][2],sacc[3][3]))));
    pm = fmaxf(pm, __shfl_xor(pm, 16));
    pm = fmaxf(pm, __shfl_xor(pm, 32));
    // ---- defer-max: rescale only if some row's max grew by >8*log2e ----
    if (!__all(pm - mrun <= 11.5415603f)){
      float mnew = fmaxf(mrun, pm);
      float alpha = __builtin_amdgcn_exp2f(mrun - mnew);
      mrun = mnew;
      lrun *= alpha;
      #pragma unroll
      for(int n=0;n<4;n++)
        #pragma unroll
        for(int r=0;r<4;r++)
          oaccT[n][r] *= alpha;
    }
    // ---- P = exp2(S' - m'), pack bf16, one b64 LDS write per ks ----
    float rs = 0.f;
    #pragma unroll
    for(int ks=0; ks<4; ks++){
      float p0 = __builtin_amdgcn_exp2f(sacc[ks][0] - mrun);
      float p1 = __builtin_amdgcn_exp2f(sacc[ks][1] - mrun);
      float p2 = __builtin_amdgcn_exp2f(sacc[ks][2] - mrun);
      float p3 = __builtin_amdgcn_exp2f(sacc[ks][3] - mrun);
      rs += (p0+p1)+(p2+p3);
      unsigned w0 = pk2bf(p0, p1);
      unsigned w1 = pk2bf(p2, p3);
      int byte0 = (col16*128 + (ks*16 + g*4)*2) ^ ((col16&7)<<4);
      unsigned long long wd = ((unsigned long long)w1 << 32) | w0;
      *(unsigned long long*)(pw + byte0) = wd;
    }
    rs += __shfl_xor(rs, 16);
    rs += __shfl_xor(rs, 32);
    lrun += rs;
    // ---- read P as B-fragment: P[q=c][k=jk*32+g*8+e] ----
    bfrag_t pf[2];
    #pragma unroll
    for(int jk=0;jk<2;jk++){
      int byteo = (col16*128 + jk*64 + g*16) ^ ((col16&7)<<4);
      pf[jk] = *(const bfrag_t*)(pw + byteo);
    }
    // ---- O^T += V^T P^T ----
    __builtin_amdgcn_s_setprio(1);
    #pragma unroll
    for(int n=0;n<4;n++){
      bfrag_t v0 = vb[(n*2+0)*64 + lane];
      bfrag_t v1 = vb[(n*2+1)*64 + lane];
      oaccT[n] = MFMA16(v0, pf[0], oaccT[n]);
      oaccT[n] = MFMA16(v1, pf[1], oaccT[n]);
    }
    __builtin_amdgcn_s_setprio(0);
    __syncthreads();   // stage(kt+1) landed; all waves done with buf[cur]
  }

  // ---- epilogue: lane owns q row qi; d = n*16 + g*4 + r ----
  {
    float inv = 1.0f / lrun;
    size_t obase = ((size_t)(b*2048 + qi))*1024 + (size_t)h*64;
    #pragma unroll
    for(int n=0;n<4;n++){
      uint2 pkd;
      pkd.x = pk2bf(oaccT[n][0]*inv, oaccT[n][1]*inv);
      pkd.y = pk2bf(oaccT[n][2]*inv, oaccT[n][3]*inv);
      *(uint2*)(O + obase + n*16 + g*4) = pkd;
    }
  }
}

// ---------------- launcher ----------------
extern "C" void kernel_launch(void* const* d_in, const int* in_sizes, int n_in,
                              void* d_out, int out_size, void* d_ws, size_t ws_size,
                              hipStream_t stream){
  const float* x     = (const float*)d_in[0];
  const float* w_qkv = (const float*)d_in[1];
  const float* w_out = (const float*)d_in[2];
  const float* b_out = (const float*)d_in[3];
  float* out = (float*)d_out;

  unsigned char* ws = (unsigned char*)d_ws;
  unsigned short* xbf   = (unsigned short*)(ws);                         // 8MB (reused as attn_out)
  unsigned short* wqkvT = (unsigned short*)(ws + (size_t)8*1024*1024);   // 6MB
  unsigned short* woutT = (unsigned short*)(ws + (size_t)14*1024*1024);  // 2MB
  unsigned short* Qb    = (unsigned short*)(ws + (size_t)16*1024*1024);  // 8MB
  unsigned short* Kb    = (unsigned short*)(ws + (size_t)24*1024*1024);  // 8MB
  unsigned short* Vtb   = (unsigned short*)(ws + (size_t)32*1024*1024);  // 8MB
  unsigned short* attno = xbf;  // alias: x_bf16 dead after GEMM1

  k_cvt<<<2048, 256, 0, stream>>>(x, xbf, 4096*1024/4);
  k_transpose<<<dim3(3072/32, 1024/32), 256, 0, stream>>>(w_qkv, wqkvT, 1024, 3072);
  k_transpose<<<dim3(1024/32, 1024/32), 256, 0, stream>>>(w_out, woutT, 1024, 1024);
  k_gemm1<<<dim3(24, 32), 256, 0, stream>>>(xbf, wqkvT, Qb, Kb, Vtb);
  k_attn<<<dim3(32, 32), 256, 0, stream>>>(Qb, Kb, Vtb, attno);
  k_gemm2<<<dim3(8, 64), 256, 0, stream>>>(attno, woutT, out, b_out);
}

// Round 10
// 111.481 us; speedup vs baseline: 1.0911x; 1.0911x over previous
//
#include <hip/hip_runtime.h>
#include <cstdint>

typedef __attribute__((ext_vector_type(8))) short bfrag_t;   // 8 x bf16 (4 VGPR)
typedef __attribute__((ext_vector_type(4))) float f32x4_t;   // MFMA acc

#define MFMA16(a,b,c) __builtin_amdgcn_mfma_f32_16x16x32_bf16((a),(b),(c),0,0,0)

__device__ __forceinline__ unsigned short f2bf(float f){
  unsigned u = __float_as_uint(f);
  unsigned r = u + 0x7fffu + ((u >> 16) & 1u);   // round-to-nearest-even
  return (unsigned short)(r >> 16);
}

// pack 2 f32 -> 2 bf16 in one u32 (lo = a, hi = b)
__device__ __forceinline__ unsigned pk2bf(float a, float b){
  unsigned r;
  asm("v_cvt_pk_bf16_f32 %0, %1, %2" : "=v"(r) : "v"(a), "v"(b));
  return r;
}

// async global->LDS, 16B per lane. LDS dest = wave-uniform base + lane*16.
__device__ __forceinline__ void gload16(const unsigned short* g, unsigned short* l){
  __builtin_amdgcn_global_load_lds(
      (const __attribute__((address_space(1))) unsigned int*)(const void*)g,
      (__attribute__((address_space(3))) unsigned int*)(void*)l,
      16, 0, 0);
}

// ---------------- merged prep: x cvt + both weight transposes ---------------
// blocks [0,2048): x f32->bf16 (float4/ushort4, 2 iters)
// blocks [2048,5120): w_qkv [1024][3072] -> bf16 [3072][1024]
// blocks [5120,6144): w_out [1024][1024] -> bf16 [1024][1024]^T
__global__ __launch_bounds__(256) void k_prep(
    const float* __restrict__ x,     unsigned short* __restrict__ xbf,
    const float* __restrict__ wqkv,  unsigned short* __restrict__ wqkvT,
    const float* __restrict__ wout,  unsigned short* __restrict__ woutT)
{
  __shared__ unsigned short tile[32][33];
  const int bid = blockIdx.x;
  const int tid = threadIdx.x;

  if (bid < 2048){
    const int n4 = 4096*1024/4;
    int i = bid*256 + tid;
    #pragma unroll
    for(int it=0; it<2; it++, i += 2048*256){
      if (i < n4){
        float4 v = ((const float4*)x)[i];
        ushort4 o;
        o.x = f2bf(v.x); o.y = f2bf(v.y); o.z = f2bf(v.z); o.w = f2bf(v.w);
        ((ushort4*)xbf)[i] = o;
      }
    }
    return;
  }

  const float* in; unsigned short* out; int R, C, idx;
  if (bid < 5120){ in = wqkv; out = wqkvT; R = 1024; C = 3072; idx = bid - 2048; }
  else           { in = wout; out = woutT; R = 1024; C = 1024; idx = bid - 5120; }
  const int nbc = C >> 5;
  const int bc = (idx % nbc) * 32, br = (idx / nbc) * 32;
  const int tx = tid & 31, ty = tid >> 5;   // ty 0..7
  #pragma unroll
  for(int i=0;i<32;i+=8){
    tile[ty+i][tx] = f2bf(in[(size_t)(br+ty+i)*C + bc + tx]);
  }
  __syncthreads();
  #pragma unroll
  for(int i=0;i<32;i+=8){
    out[(size_t)(bc+ty+i)*R + br + tx] = tile[tx][ty+i];
  }
}

// ---------------- GEMM1: x @ w_qkv -> Q (scaled), K image, V image ----------
// 128x128 tile, BK=64 single-buffer (R8 structure), gload_lds staging with
// 8-slot source-side XOR swizzle (gs = s ^ (row&7)), matching XOR on read.
// 1-D grid 768 + XCD-chunked swizzle: same-XCD blocks are m-contiguous ->
// A-panels + B stay warm in that XCD's L2 (T1).
// Block-uniform branch: bn<2048 -> swapped core (Q/K, uint2 stores);
//                       bn>=2048 -> normal core (V image, uint2 stores).
__global__ __launch_bounds__(256) void k_gemm1(
    const unsigned short* __restrict__ A,    // x bf16 [4096][1024]
    const unsigned short* __restrict__ Bt,   // wqkvT [3072][1024]
    unsigned short* __restrict__ Qo, unsigned short* __restrict__ Kimg,
    unsigned short* __restrict__ Vimg)
{
  __shared__ unsigned short ldsA[128*64];
  __shared__ unsigned short ldsB[128*64];

  const int tid = threadIdx.x;
  const int lane = tid & 63;
  const int w = tid >> 6;
  const int wr = w >> 1, wc = w & 1;
  const int col16 = lane & 15, g = lane >> 4;

  // XCD-chunked bijective swizzle (768 % 8 == 0): XCD x gets swz [x*96,(x+1)*96)
  const int L = blockIdx.x;
  const int swz = (L & 7) * 96 + (L >> 3);
  const int bm = (swz / 24) * 128;
  const int bn = (swz % 24) * 128;
  const int K = 1024;
  const int SWAP = (bn < 2048) ? 1 : 0;

  f32x4_t acc[4][4];
  #pragma unroll
  for(int i=0;i<4;i++)
    #pragma unroll
    for(int j=0;j<4;j++) acc[i][j] = (f32x4_t)0.0f;

  for(int k0=0; k0<K; k0+=64){
    __syncthreads();   // all waves done reading previous tile
    #pragma unroll
    for(int i=0; i<4; i++){                 // A: 128 rows x 8 slots = 1024 units
      int u = i*256 + tid;
      int row = u>>3, s = u&7, gs = s ^ (row&7);
      gload16(A + (size_t)(bm+row)*K + k0 + gs*8, ldsA + (i*256 + w*64)*8);
    }
    #pragma unroll
    for(int i=0; i<4; i++){                 // B: 1024 units
      int u = i*256 + tid;
      int row = u>>3, s = u&7, gs = s ^ (row&7);
      gload16(Bt + (size_t)(bn+row)*K + k0 + gs*8, ldsB + (i*256 + w*64)*8);
    }
    __syncthreads();   // loads landed (compiler drains vmcnt before barrier)
    #pragma unroll
    for(int kk=0; kk<2; kk++){
      bfrag_t af[4], bfr[4];
      #pragma unroll
      for(int mi=0;mi<4;mi++){
        int row = wr*64 + mi*16 + col16;
        int slot = (kk*4 + g) ^ (row&7);
        af[mi] = *(const bfrag_t*)(ldsA + row*64 + slot*8);
      }
      #pragma unroll
      for(int ni=0;ni<4;ni++){
        int row = wc*64 + ni*16 + col16;
        int slot = (kk*4 + g) ^ (row&7);
        bfr[ni] = *(const bfrag_t*)(ldsB + row*64 + slot*8);
      }
      if (SWAP){
        #pragma unroll
        for(int mi=0;mi<4;mi++)
          #pragma unroll
          for(int ni=0;ni<4;ni++)
            acc[mi][ni] = MFMA16(bfr[ni], af[mi], acc[mi][ni]);
      } else {
        #pragma unroll
        for(int mi=0;mi<4;mi++)
          #pragma unroll
          for(int ni=0;ni<4;ni++)
            acc[mi][ni] = MFMA16(af[mi], bfr[ni], acc[mi][ni]);
      }
    }
  }

  if (bn < 2048){
    // lane holds C[s = row][4 consecutive n]; which uniform per block
    const int which = bn >> 10;   // 0 = Q, 1 = K
    #pragma unroll
    for(int mi=0;mi<4;mi++){
      int s_full = bm + wr*64 + mi*16 + col16;
      int b = s_full >> 11, sq = s_full & 2047;
      #pragma unroll
      for(int ni=0;ni<4;ni++){
        int n0 = bn + wc*64 + ni*16 + g*4;
        int h = (n0 & 1023) >> 6;
        int d0 = n0 & 63;
        size_t bh = (size_t)(b*16 + h);
        float v0 = acc[mi][ni][0], v1 = acc[mi][ni][1];
        float v2 = acc[mi][ni][2], v3 = acc[mi][ni][3];
        if (which == 0){
          const float sc = 0.18033688f;   // 0.125 * log2(e): exp2-domain softmax
          uint2 pkd; pkd.x = pk2bf(v0*sc, v1*sc); pkd.y = pk2bf(v2*sc, v3*sc);
          *(uint2*)(Qo + (bh*2048 + sq)*64 + d0) = pkd;
        } else {
          int kt = sq >> 6, rr = sq & 63;
          int ks = rr >> 4, c16i = rr & 15;
          int dk = d0 >> 5, g3 = (d0 >> 3) & 3, e0 = d0 & 7;
          uint2 pkd; pkd.x = pk2bf(v0, v1); pkd.y = pk2bf(v2, v3);
          size_t off = bh*131072 + (size_t)kt*4096
                     + (size_t)(ks*2 + dk)*512 + (size_t)(g3*16 + c16i)*8 + e0;
          *(uint2*)(Kimg + off) = pkd;
        }
      }
    }
  } else {
    // V: lane holds 4 consecutive s (packs along e) -> uint2
    #pragma unroll
    for(int mi=0;mi<4;mi++){
      int s0 = bm + wr*64 + mi*16 + g*4;
      int b = s0 >> 11, sq0 = s0 & 2047;
      int kt = sq0 >> 6, sc0 = sq0 & 63;
      int jk = sc0 >> 5, g3 = (sc0 >> 3) & 3, e0 = sc0 & 7;
      #pragma unroll
      for(int ni=0;ni<4;ni++){
        int ncol = bn + wc*64 + ni*16 + col16;
        int h = (ncol & 1023) >> 6;
        int d64 = ncol & 63;
        int nimg = d64 >> 4, c16i = d64 & 15;
        size_t bh = (size_t)(b*16 + h);
        uint2 pkd;
        pkd.x = pk2bf(acc[mi][ni][0], acc[mi][ni][1]);
        pkd.y = pk2bf(acc[mi][ni][2], acc[mi][ni][3]);
        size_t off = bh*131072 + (size_t)kt*4096
                   + (size_t)(nimg*2 + jk)*512 + (size_t)(g3*16 + c16i)*8 + e0;
        *(uint2*)(Vimg + off) = pkd;
      }
    }
  }
}

// ---------------- GEMM2: attn_out @ w_out + bias -> f32 (BK=64) -------------
// 64x128 tile, 4 waves (1x4), single-buffer, XCD-chunked swizzle (512%8==0).
__global__ __launch_bounds__(256) void k_gemm2(
    const unsigned short* __restrict__ A,    // attn_out bf16 [4096][1024]
    const unsigned short* __restrict__ Bt,   // woutT [1024][1024]
    float* __restrict__ Co, const float* __restrict__ bias)
{
  __shared__ unsigned short ldsA[64*64];
  __shared__ unsigned short ldsB[128*64];

  const int tid = threadIdx.x;
  const int lane = tid & 63;
  const int w = tid >> 6;
  const int wc = w;                       // WM=1, WN=4
  const int col16 = lane & 15, g = lane >> 4;

  const int L = blockIdx.x;
  const int swz = (L & 7) * 64 + (L >> 3);
  const int bm = (swz >> 3) * 64;         // 64 m-blocks
  const int bn = (swz & 7) * 128;         // 8 n-blocks
  const int K = 1024, N = 1024;

  f32x4_t acc[4][2];
  #pragma unroll
  for(int i=0;i<4;i++)
    #pragma unroll
    for(int j=0;j<2;j++) acc[i][j] = (f32x4_t)0.0f;

  for(int k0=0; k0<K; k0+=64){
    __syncthreads();
    #pragma unroll
    for(int i=0; i<2; i++){                 // A: 64 rows x 8 slots = 512 units
      int u = i*256 + tid;
      int row = u>>3, s = u&7, gs = s ^ (row&7);
      gload16(A + (size_t)(bm+row)*K + k0 + gs*8, ldsA + (i*256 + w*64)*8);
    }
    #pragma unroll
    for(int i=0; i<4; i++){                 // B: 1024 units
      int u = i*256 + tid;
      int row = u>>3, s = u&7, gs = s ^ (row&7);
      gload16(Bt + (size_t)(bn+row)*K + k0 + gs*8, ldsB + (i*256 + w*64)*8);
    }
    __syncthreads();
    #pragma unroll
    for(int kk=0; kk<2; kk++){
      bfrag_t af[4], bfr[2];
      #pragma unroll
      for(int mi=0;mi<4;mi++){
        int row = mi*16 + col16;
        int slot = (kk*4 + g) ^ (row&7);
        af[mi] = *(const bfrag_t*)(ldsA + row*64 + slot*8);
      }
      #pragma unroll
      for(int ni=0;ni<2;ni++){
        int row = wc*32 + ni*16 + col16;
        int slot = (kk*4 + g) ^ (row&7);
        bfr[ni] = *(const bfrag_t*)(ldsB + row*64 + slot*8);
      }
      #pragma unroll
      for(int mi=0;mi<4;mi++)
        #pragma unroll
        for(int ni=0;ni<2;ni++)
          acc[mi][ni] = MFMA16(af[mi], bfr[ni], acc[mi][ni]);
    }
  }

  #pragma unroll
  for(int mi=0;mi<4;mi++){
    int mrow = bm + mi*16 + g*4;
    #pragma unroll
    for(int ni=0;ni<2;ni++){
      int ncol = bn + wc*32 + ni*16 + col16;
      float bb = bias[ncol];
      #pragma unroll
      for(int r=0;r<4;r++){
        Co[(size_t)(mrow+r)*N + ncol] = acc[mi][ni][r] + bb;
      }
    }
  }
}

// ---------------- causal flash attention (v8: balanced cohorts + setprio) ----
// grid (32 bh, 32 y). All 1024 blocks co-resident (4/CU); a CU's cohort is
// y = {j, j+8, j+16, j+24}. Map idx=(y&7)*4+(y>>3); qt=(idx&1)?31-(idx>>1):idx>>1
// -> every cohort's nkt sum = 66 (exact balance). bh = blockIdx.x keeps each
// head's 32 blocks on one XCD (linear id % 8 == bh % 8).
__global__ __launch_bounds__(256, 4) void k_attn(
    const unsigned short* __restrict__ Q,
    const unsigned short* __restrict__ Kimg,
    const unsigned short* __restrict__ Vimg,
    unsigned short* __restrict__ O)
{
  __shared__ unsigned short kls[2*4096];     // K tiles, double-buffered (8KB each)
  __shared__ unsigned short vls[2*4096];     // V tiles
  __shared__ unsigned short plds[4*1024];    // per-wave 16x64 P tile, XOR-swizzled
  const int lane = threadIdx.x & 63;
  const int w = threadIdx.x >> 6;
  const int col16 = lane & 15, g = lane >> 4;
  const int bh = blockIdx.x;
  const int y = blockIdx.y;
  const int idx = (y & 7)*4 + (y >> 3);
  const int qt = (idx & 1) ? (31 - (idx >> 1)) : (idx >> 1);
  const int b = bh >> 4, h = bh & 15;

  const unsigned short* Qb = Q    + (size_t)bh*2048*64;
  const unsigned short* Kb = Kimg + (size_t)bh*131072;
  const unsigned short* Vb = Vimg + (size_t)bh*131072;
  char* pw = (char*)(plds + w*1024);

  auto stage = [&](int kt, int bsel){
    const unsigned short* gk = Kb + (size_t)kt*4096;
    const unsigned short* gv = Vb + (size_t)kt*4096;
    unsigned short* lk = kls + bsel*4096;
    unsigned short* lv = vls + bsel*4096;
    #pragma unroll
    for(int c=0;c<2;c++){
      int chunk = w*2 + c;               // 0..7, 1KB each
      int u = chunk*64 + lane;           // 16B-unit index
      gload16(gk + u*8, lk + chunk*512);
      gload16(gv + u*8, lv + chunk*512);
    }
  };

  const int qrow0 = qt*64 + w*16;
  const int nkt = qt + 1;
  const int qi = qrow0 + col16;          // this lane's q row

  bfrag_t qf[2];
  #pragma unroll
  for(int dk=0;dk<2;dk++)
    qf[dk] = *(const bfrag_t*)(Qb + (size_t)(qrow0 + col16)*64 + dk*32 + g*8);

  f32x4_t oaccT[4];
  #pragma unroll
  for(int n=0;n<4;n++) oaccT[n] = (f32x4_t)0.0f;
  float mrun = -1e30f, lrun = 0.f;

  stage(0, 0);
  __syncthreads();

  #pragma unroll 1
  for(int kt=0; kt<nkt; kt++){
    const int cur = kt & 1;
    if (kt+1 < nkt) stage(kt+1, cur^1);

    const bfrag_t* kb = (const bfrag_t*)(kls + cur*4096);
    const bfrag_t* vb = (const bfrag_t*)(vls + cur*4096);

    // ---- S'^T = K Q^T (exp2 domain): sacc[ks][r] = S'[q=qi][k=kt*64+ks*16+g*4+r]
    f32x4_t sacc[4];
    __builtin_amdgcn_s_setprio(1);
    #pragma unroll
    for(int ks=0; ks<4; ks++){
      bfrag_t kf0 = kb[(ks*2+0)*64 + lane];
      bfrag_t kf1 = kb[(ks*2+1)*64 + lane];
      f32x4_t c = (f32x4_t)0.0f;
      c = MFMA16(kf0, qf[0], c);
      c = MFMA16(kf1, qf[1], c);
      sacc[ks] = c;
    }
    __builtin_amdgcn_s_setprio(0);
    // ---- causal mask (diagonal tile only) ----
    if (kt == qt){
      const int kbase = kt*64;
      #pragma unroll
      for(int ks=0; ks<4; ks++)
        #pragma unroll
        for(int r=0;r<4;r++){
          int kj = kbase + ks*16 + g*4 + r;
          if (kj > qi) sacc[ks][r] = -1e30f;
        }
    }
    // ---- per-lane row max + 2 shfl ----
    float pm = fmaxf(
        fmaxf(fmaxf(fmaxf(sacc[0][0],sacc[0][1]),fmaxf(sacc[0][2],sacc[0][3])),
              fmaxf(fmaxf(sacc[1][0],sacc[1][1]),fmaxf(sacc[1][2],sacc[1][3]))),
        fmaxf(fmaxf(fmaxf(sacc[2][0],sacc[2][1]),fmaxf(sacc[2][2],sacc[2][3])),
              fmaxf(fmaxf(sacc[3][0],sacc[3][1]),fmaxf(sacc[3][2],sacc[3][3]))));
    pm = fmaxf(pm, __shfl_xor(pm, 16));
    pm = fmaxf(pm, __shfl_xor(pm, 32));
    // ---- defer-max: rescale only if some row's max grew by >8*log2e ----
    if (!__all(pm - mrun <= 11.5415603f)){
      float mnew = fmaxf(mrun, pm);
      float alpha = __builtin_amdgcn_exp2f(mrun - mnew);
      mrun = mnew;
      lrun *= alpha;
      #pragma unroll
      for(int n=0;n<4;n++)
        #pragma unroll
        for(int r=0;r<4;r++)
          oaccT[n][r] *= alpha;
    }
    // ---- P = exp2(S' - m'), pack bf16, one b64 LDS write per ks ----
    float rs = 0.f;
    #pragma unroll
    for(int ks=0; ks<4; ks++){
      float p0 = __builtin_amdgcn_exp2f(sacc[ks][0] - mrun);
      float p1 = __builtin_amdgcn_exp2f(sacc[ks][1] - mrun);
      float p2 = __builtin_amdgcn_exp2f(sacc[ks][2] - mrun);
      float p3 = __builtin_amdgcn_exp2f(sacc[ks][3] - mrun);
      rs += (p0+p1)+(p2+p3);
      unsigned w0 = pk2bf(p0, p1);
      unsigned w1 = pk2bf(p2, p3);
      int byte0 = (col16*128 + (ks*16 + g*4)*2) ^ ((col16&7)<<4);
      unsigned long long wd = ((unsigned long long)w1 << 32) | w0;
      *(unsigned long long*)(pw + byte0) = wd;
    }
    rs += __shfl_xor(rs, 16);
    rs += __shfl_xor(rs, 32);
    lrun += rs;
    // ---- read P as B-fragment: P[q=c][k=jk*32+g*8+e] ----
    bfrag_t pf[2];
    #pragma unroll
    for(int jk=0;jk<2;jk++){
      int byteo = (col16*128 + jk*64 + g*16) ^ ((col16&7)<<4);
      pf[jk] = *(const bfrag_t*)(pw + byteo);
    }
    // ---- O^T += V^T P^T ----
    __builtin_amdgcn_s_setprio(1);
    #pragma unroll
    for(int n=0;n<4;n++){
      bfrag_t v0 = vb[(n*2+0)*64 + lane];
      bfrag_t v1 = vb[(n*2+1)*64 + lane];
      oaccT[n] = MFMA16(v0, pf[0], oaccT[n]);
      oaccT[n] = MFMA16(v1, pf[1], oaccT[n]);
    }
    __builtin_amdgcn_s_setprio(0);
    __syncthreads();   // stage(kt+1) landed; all waves done with buf[cur]
  }

  // ---- epilogue: lane owns q row qi; d = n*16 + g*4 + r ----
  {
    float inv = 1.0f / lrun;
    size_t obase = ((size_t)(b*2048 + qi))*1024 + (size_t)h*64;
    #pragma unroll
    for(int n=0;n<4;n++){
      uint2 pkd;
      pkd.x = pk2bf(oaccT[n][0]*inv, oaccT[n][1]*inv);
      pkd.y = pk2bf(oaccT[n][2]*inv, oaccT[n][3]*inv);
      *(uint2*)(O + obase + n*16 + g*4) = pkd;
    }
  }
}

// ---------------- launcher ----------------
extern "C" void kernel_launch(void* const* d_in, const int* in_sizes, int n_in,
                              void* d_out, int out_size, void* d_ws, size_t ws_size,
                              hipStream_t stream){
  const float* x     = (const float*)d_in[0];
  const float* w_qkv = (const float*)d_in[1];
  const float* w_out = (const float*)d_in[2];
  const float* b_out = (const float*)d_in[3];
  float* out = (float*)d_out;

  unsigned char* ws = (unsigned char*)d_ws;
  unsigned short* xbf   = (unsigned short*)(ws);                         // 8MB (reused as attn_out)
  unsigned short* wqkvT = (unsigned short*)(ws + (size_t)8*1024*1024);   // 6MB
  unsigned short* woutT = (unsigned short*)(ws + (size_t)14*1024*1024);  // 2MB
  unsigned short* Qb    = (unsigned short*)(ws + (size_t)16*1024*1024);  // 8MB
  unsigned short* Kb    = (unsigned short*)(ws + (size_t)24*1024*1024);  // 8MB
  unsigned short* Vtb   = (unsigned short*)(ws + (size_t)32*1024*1024);  // 8MB
  unsigned short* attno = xbf;  // alias: x_bf16 dead after GEMM1

  k_prep<<<6144, 256, 0, stream>>>(x, xbf, w_qkv, wqkvT, w_out, woutT);
  k_gemm1<<<768, 256, 0, stream>>>(xbf, wqkvT, Qb, Kb, Vtb);
  k_attn<<<dim3(32, 32), 256, 0, stream>>>(Qb, Kb, Vtb, attno);
  k_gemm2<<<512, 256, 0, stream>>>(attno, woutT, out, b_out);
}